// Round 18
// baseline (237.539 us; speedup 1.0000x reference)
//
#include <hip/hip_runtime.h>
#include <hip/hip_bf16.h>
#include <math.h>

#define B_ 4
#define S_ 2048
#define C_ 1024
#define H_ 16
#define D_ 64
#define M_ (B_*S_)      // 8192
#define NQKV (3*C_)     // 3072
#define KDIM C_         // 1024

typedef float f32x4 __attribute__((ext_vector_type(4)));
typedef float f32x16 __attribute__((ext_vector_type(16)));
typedef short bf16x8 __attribute__((ext_vector_type(8)));

static __device__ __forceinline__ ushort f2bf(float f){
    __hip_bfloat16 h = __float2bfloat16(f);
    union { __hip_bfloat16 b; ushort u; } v; v.b = h;
    return v.u;
}

// async global->LDS, 16B per lane; lds dest = wave-uniform base + lane*16 (linear)
static __device__ __forceinline__ void gload16(const ushort* g, ushort* l){
    __builtin_amdgcn_global_load_lds((__attribute__((address_space(1))) void*)g,
                                     (__attribute__((address_space(3))) void*)l,
                                     16, 0, 0);
}

// ---------------- fused prep: conv x->bf16 | transpose Wqkv | transpose Wproj | cs table ----
__global__ void k_prep(const float* __restrict__ x, const float* __restrict__ Wqkv,
                       const float* __restrict__ Wproj,
                       ushort* __restrict__ xb, ushort* __restrict__ wqt,
                       ushort* __restrict__ wpt, unsigned* __restrict__ csT){
    __shared__ float tile[32][33];
    int blk = blockIdx.x, tid = threadIdx.x;
    if (blk < 2048){
        const int n4 = M_*KDIM/4;
        for (int i = blk*256 + tid; i < n4; i += 2048*256){
            float4 v = *(const float4*)(x + (size_t)i*4);
            ushort4 o = { f2bf(v.x), f2bf(v.y), f2bf(v.z), f2bf(v.w) };
            *(ushort4*)(xb + (size_t)i*4) = o;
        }
    } else if (blk < 5120){
        int t = blk - 2048;                      // 96 x 32 tiles
        int c0 = (t % 96)*32, r0 = (t / 96)*32;
        int tx = tid & 31, ty = tid >> 5;
        for (int j = ty; j < 32; j += 8)
            tile[j][tx] = Wqkv[(size_t)(r0 + j)*NQKV + c0 + tx];
        __syncthreads();
        for (int j = ty; j < 32; j += 8)
            wqt[(size_t)(c0 + tx)*KDIM + r0 + j] = f2bf(tile[j][tx]);
    } else if (blk < 6144){
        int t = blk - 5120;                      // 32 x 32 tiles
        int c0 = (t & 31)*32, r0 = (t >> 5)*32;
        int tx = tid & 31, ty = tid >> 5;
        for (int j = ty; j < 32; j += 8)
            tile[j][tx] = Wproj[(size_t)(r0 + j)*C_ + c0 + tx];
        __syncthreads();
        for (int j = ty; j < 32; j += 8)
            wpt[(size_t)(c0 + tx)*KDIM + r0 + j] = f2bf(tile[j][tx]);
    } else {
        int t = (blk - 6144)*256 + tid;          // S_*D_ = 131072 = 512*256
        int pos = t >> 6, d = t & 63;
        float invf = powf(10000.0f, -(float)(d & 31) / 32.0f);
        float ang = (float)pos * invf;
        csT[t] = (unsigned)f2bf(cosf(ang)) | ((unsigned)f2bf(sinf(ang)) << 16);
    }
}

// ---------------- QKV GEMM: 128x128 tile, 256 threads, 32 KB LDS -> 5 blocks/CU ----------------
// r6 skeleton (dbuf + gload_lds + one barrier/K-step); q pre-scaled by 0.125*log2(e).
__launch_bounds__(256, 5)
__global__ void k_qkv(const ushort* __restrict__ xb, const ushort* __restrict__ wt,
                      const float* __restrict__ bqkv, const unsigned* __restrict__ csT,
                      ushort* __restrict__ qb, ushort* __restrict__ kb, ushort* __restrict__ vT){
    __shared__ __align__(16) ushort As[2][128][32];
    __shared__ __align__(16) ushort Bs[2][128][32];
    int bid = blockIdx.x;                       // 1536 blocks, XCD-grouped (A-panel-major)
    int lin = (bid & 7)*192 + (bid >> 3);
    int bx = lin % 24, by = lin / 24;           // by 0..63
    int M0 = by*128, N0 = bx*128;
    int tid = threadIdx.x;
    int wid = tid >> 6, lane = tid & 63;
    int wm = wid >> 1, wn = wid & 1;            // 2M x 2N waves, 64x64 each
    int lrow = lane & 15, lk = lane >> 4;
    int swu = (lrow >> 1) & 3;                  // read-side XOR (row bits [2:1])

    int scol = (((tid & 3) ^ ((tid >> 3) & 3))) * 8;     // pre-swizzled source column
    const ushort* gA0 = &xb[(size_t)(M0 + (tid >> 2))*KDIM + scol];
    const ushort* gB0 = &wt[(size_t)(N0 + (tid >> 2))*KDIM + scol];
    const size_t half = (size_t)64*KDIM;

    f32x4 acc[4][4] = {};
    int cur = 0;
    // prologue: stage K-step 0 into buf 0 (4 x 4KB calls)
    gload16(gA0,        &As[0][wid*16][0]);
    gload16(gA0 + half, &As[0][64 + wid*16][0]);
    gload16(gB0,        &Bs[0][wid*16][0]);
    gload16(gB0 + half, &Bs[0][64 + wid*16][0]);
    __syncthreads();

    for (int k0 = 0; k0 < KDIM; k0 += 32){
        int nk = k0 + 32;
        if (nk < KDIM){                          // prefetch next step into other buffer
            gload16(gA0 + nk,        &As[cur^1][wid*16][0]);
            gload16(gA0 + half + nk, &As[cur^1][64 + wid*16][0]);
            gload16(gB0 + nk,        &Bs[cur^1][wid*16][0]);
            gload16(gB0 + half + nk, &Bs[cur^1][64 + wid*16][0]);
        }
        bf16x8 a[4], b[4];
#pragma unroll
        for (int mi = 0; mi < 4; mi++)
            a[mi] = *(const bf16x8*)(&As[cur][wm*64 + mi*16 + lrow][(lk ^ swu)*8]);
#pragma unroll
        for (int ni = 0; ni < 4; ni++)
            b[ni] = *(const bf16x8*)(&Bs[cur][wn*64 + ni*16 + lrow][(lk ^ swu)*8]);
#pragma unroll
        for (int mi = 0; mi < 4; mi++)
#pragma unroll
            for (int ni = 0; ni < 4; ni++)
                acc[mi][ni] = __builtin_amdgcn_mfma_f32_16x16x32_bf16(a[mi], b[ni], acc[mi][ni], 0, 0, 0);
        __syncthreads();                          // drains prefetch vmcnt + syncs readers
        cur ^= 1;
    }
#pragma unroll
    for (int mi = 0; mi < 4; mi++)
#pragma unroll
    for (int ni = 0; ni < 4; ni++){
        int gn = N0 + wn*64 + ni*16 + lrow;
        float bias = bqkv[gn];
        int which = gn >> 10;       // 0=q 1=k 2=v (uniform per block: 1024 % 128 == 0)
        int cn = gn & 1023;
        int h = cn >> 6, d = cn & 63;
        int gm0 = M0 + wm*64 + mi*16 + lk*4;
        int bb = gm0 >> 11, pos0 = gm0 & 2047;
        if (which == 2){
            ushort4 o = { f2bf(acc[mi][ni][0] + bias), f2bf(acc[mi][ni][1] + bias),
                          f2bf(acc[mi][ni][2] + bias), f2bf(acc[mi][ni][3] + bias) };
            *(ushort4*)(&vT[(((size_t)(bb*H_ + h))*D_ + d)*S_ + pos0]) = o;
        } else {
#pragma unroll
            for (int rr = 0; rr < 4; rr++){
                float val = acc[mi][ni][rr] + bias;
                float rot = __shfl_xor(val, 1);       // partner col (d^1), bias included
                unsigned cs = csT[(pos0 + rr)*64 + d]; // [pos][d]: d-contiguous, coalesced
                float c = __uint_as_float(cs << 16);
                float s = __uint_as_float(cs & 0xffff0000u);
                float o = val*c + ((d & 1) ? rot : -rot)*s;
                if (which == 0) o *= 0.18033688f;     // (1/sqrt(D)) * log2(e)
                int out_idx = (((bb*H_ + h)*S_) + pos0 + rr)*D_ + d;
                ((which == 0) ? qb : kb)[out_idx] = f2bf(o);
            }
        }
    }
}

// ---------------- proj GEMM: 128x128 tile, 256 threads, 5 blocks/CU + bias -> fp32 out ----------------
__launch_bounds__(256, 5)
__global__ void k_proj(const ushort* __restrict__ ab, const ushort* __restrict__ wt,
                       const float* __restrict__ bias, float* __restrict__ out){
    __shared__ __align__(16) ushort As[2][128][32];
    __shared__ __align__(16) ushort Bs[2][128][32];
    int bid = blockIdx.x;                       // 512 blocks, XCD-grouped
    int lin = (bid & 7)*64 + (bid >> 3);
    int bx = lin & 7, by = lin >> 3;            // 8 x 64
    int M0 = by*128, N0 = bx*128;
    int tid = threadIdx.x;
    int wid = tid >> 6, lane = tid & 63;
    int wm = wid >> 1, wn = wid & 1;
    int lrow = lane & 15, lk = lane >> 4;
    int swu = (lrow >> 1) & 3;

    int scol = (((tid & 3) ^ ((tid >> 3) & 3))) * 8;
    const ushort* gA0 = &ab[(size_t)(M0 + (tid >> 2))*KDIM + scol];
    const ushort* gB0 = &wt[(size_t)(N0 + (tid >> 2))*KDIM + scol];
    const size_t half = (size_t)64*KDIM;

    f32x4 acc[4][4] = {};
    int cur = 0;
    gload16(gA0,        &As[0][wid*16][0]);
    gload16(gA0 + half, &As[0][64 + wid*16][0]);
    gload16(gB0,        &Bs[0][wid*16][0]);
    gload16(gB0 + half, &Bs[0][64 + wid*16][0]);
    __syncthreads();

    for (int k0 = 0; k0 < KDIM; k0 += 32){
        int nk = k0 + 32;
        if (nk < KDIM){
            gload16(gA0 + nk,        &As[cur^1][wid*16][0]);
            gload16(gA0 + half + nk, &As[cur^1][64 + wid*16][0]);
            gload16(gB0 + nk,        &Bs[cur^1][wid*16][0]);
            gload16(gB0 + half + nk, &Bs[cur^1][64 + wid*16][0]);
        }
        bf16x8 a[4], b[4];
#pragma unroll
        for (int mi = 0; mi < 4; mi++)
            a[mi] = *(const bf16x8*)(&As[cur][wm*64 + mi*16 + lrow][(lk ^ swu)*8]);
#pragma unroll
        for (int ni = 0; ni < 4; ni++)
            b[ni] = *(const bf16x8*)(&Bs[cur][wn*64 + ni*16 + lrow][(lk ^ swu)*8]);
#pragma unroll
        for (int mi = 0; mi < 4; mi++)
#pragma unroll
            for (int ni = 0; ni < 4; ni++)
                acc[mi][ni] = __builtin_amdgcn_mfma_f32_16x16x32_bf16(a[mi], b[ni], acc[mi][ni], 0, 0, 0);
        __syncthreads();
        cur ^= 1;
    }
#pragma unroll
    for (int mi = 0; mi < 4; mi++)
#pragma unroll
    for (int ni = 0; ni < 4; ni++){
        int gn = N0 + wn*64 + ni*16 + lrow;
        float bv = bias[gn];
#pragma unroll
        for (int rr = 0; rr < 4; rr++){
            int gm = M0 + wm*64 + mi*16 + lk*4 + rr;
            out[(size_t)gm*C_ + gn] = acc[mi][ni][rr] + bv;
        }
    }
}

// ---------------- causal flash attention: 8 waves x 32 q-rows, NO-MAX softmax, KVBLK=128 ----
// One barrier pair per 128 keys.  Complementary qt mapping: CU pair sums to constant work.
__launch_bounds__(512, 2)
__global__ void k_attn(const ushort* __restrict__ qb, const ushort* __restrict__ kb,
                       const ushort* __restrict__ vT, ushort* __restrict__ ob){
    __shared__ __align__(16) ushort Ks[2][64][64];
    __shared__ __align__(16) ushort Vs[2][64][64];
    int id = blockIdx.x;
    int bh = id & 63;
    int g  = id >> 6;                           // 0..7
    int qt = (g < 4) ? (7 - g) : (g - 4);       // pairs (7,0),(6,1),(5,2),(4,3)
    int bb = bh >> 4, h = bh & 15;
    int tid = threadIdx.x, wid = tid >> 6, lane = tid & 63;
    int lq = lane & 31, hi = lane >> 5;
    const ushort* qp = qb + (size_t)bh*S_*D_;
    const ushort* kp = kb + (size_t)bh*S_*D_;
    const ushort* vp = vT + (size_t)bh*D_*S_;
    int qw = qt*256 + wid*32;
    int qrow = qw + lq;
    int swz = lq & 7;

    bf16x8 fq[4];                               // Q B-frags: k = c*16 + hi*8 + e
#pragma unroll
    for (int c = 0; c < 4; c++)
        fq[c] = *(const bf16x8*)(&qp[qrow*D_ + c*16 + hi*8]);

    f32x16 acc0 = {}, acc1 = {};                // O^T[d][q]: d = (reg&3)+8*(reg>>2)+4*hi (+32)
    float l = 0.0f;                             // per-lane partial (its key half)

    int sr = tid >> 3, su = tid & 7;            // 512 threads: 64 rows x 8 units per half
    int swr = (su ^ (sr & 7)) * 8;              // swizzled 16B-unit for stage writes
    int sc = su * 8;

    // prologue: tile 0 (128 keys = 2 halves) into regs
    int4 ra0 = *(const int4*)(&kp[sr*D_ + sc]);
    int4 ra1 = *(const int4*)(&kp[(64 + sr)*D_ + sc]);
    int4 rc0 = *(const int4*)(&vp[(size_t)sr*S_ + sc]);
    int4 rc1 = *(const int4*)(&vp[(size_t)sr*S_ + 64 + sc]);

    int nit = 2*qt + 2;                         // 128-key tiles
    for (int it = 0; it < nit; ++it){
        *(int4*)(&Ks[0][sr][swr]) = ra0;
        *(int4*)(&Ks[1][sr][swr]) = ra1;
        *(int4*)(&Vs[0][sr][swr]) = rc0;
        *(int4*)(&Vs[1][sr][swr]) = rc1;
        __syncthreads();
        if (it + 1 < nit){
            int jn = (it + 1)*128;              // prefetch next 128-key tile; lands during compute
            ra0 = *(const int4*)(&kp[(jn + sr)*D_ + sc]);
            ra1 = *(const int4*)(&kp[(jn + 64 + sr)*D_ + sc]);
            rc0 = *(const int4*)(&vp[(size_t)sr*S_ + jn + sc]);
            rc1 = *(const int4*)(&vp[(size_t)sr*S_ + jn + 64 + sc]);
        }
#pragma unroll
        for (int hf = 0; hf < 2; hf++){
            int relh = qw - it*128 - hf*64;     // wave-uniform; 32-aligned
            if (relh < 0) continue;
            bool diag0 = (relh == 0);
            bool have1 = (relh >= 32);
            bool diag1 = (relh == 32);
            f32x16 z0 = {}, z1 = {};
            __builtin_amdgcn_s_setprio(1);
#pragma unroll
            for (int c = 0; c < 4; c++){
                bf16x8 kf = *(const bf16x8*)(&Ks[hf][lq][((2*c + hi) ^ swz)*8]);
                z0 = __builtin_amdgcn_mfma_f32_32x32x16_bf16(kf, fq[c], z0, 0, 0, 0);
            }
            if (have1){
#pragma unroll
                for (int c = 0; c < 4; c++){
                    bf16x8 kf = *(const bf16x8*)(&Ks[hf][32 + lq][((2*c + hi) ^ swz)*8]);
                    z1 = __builtin_amdgcn_mfma_f32_32x32x16_bf16(kf, fq[c], z1, 0, 0, 0);
                }
            }
            __builtin_amdgcn_s_setprio(0);
            if (diag0){
#pragma unroll
                for (int r = 0; r < 16; r++)
                    if (((r & 3) + 8*(r >> 2) + 4*hi) > lq) z0[r] = -1e30f;
            }
            if (diag1){
#pragma unroll
                for (int r = 0; r < 16; r++)
                    if (((r & 3) + 8*(r >> 2) + 4*hi) > lq) z1[r] = -1e30f;
            }
            // no-max softmax: p = exp2(z) direct; masked -> exp2(-1e30) = 0
#pragma unroll
            for (int r = 0; r < 16; r++){ z0[r] = exp2f(z0[r]); l += z0[r]; }
            if (have1){
#pragma unroll
                for (int r = 0; r < 16; r++){ z1[r] = exp2f(z1[r]); l += z1[r]; }
            }

            // P->bf16 B-frags in-register: per 16-key sub, 4 cvt_pk + 2 permlane32_swap.
#define PV_SUB(zz, r0_, su_, t_) do {                                             \
    unsigned w0, w1, w2, w3;                                                      \
    asm("v_cvt_pk_bf16_f32 %0, %1, %2" : "=v"(w0) : "v"(zz[r0_+0]), "v"(zz[r0_+1])); \
    asm("v_cvt_pk_bf16_f32 %0, %1, %2" : "=v"(w1) : "v"(zz[r0_+2]), "v"(zz[r0_+3])); \
    asm("v_cvt_pk_bf16_f32 %0, %1, %2" : "=v"(w2) : "v"(zz[r0_+4]), "v"(zz[r0_+5])); \
    asm("v_cvt_pk_bf16_f32 %0, %1, %2" : "=v"(w3) : "v"(zz[r0_+6]), "v"(zz[r0_+7])); \
    auto s02 = __builtin_amdgcn_permlane32_swap(w0, w2, false, false);             \
    auto s13 = __builtin_amdgcn_permlane32_swap(w1, w3, false, false);             \
    union { unsigned u[4]; bf16x8 v; } pf;                                        \
    pf.u[0] = s02[0]; pf.u[1] = s13[0]; pf.u[2] = s02[1]; pf.u[3] = s13[1];       \
    bf16x8 vf0 = *(const bf16x8*)(&Vs[hf][lq][(((su_)*4 + (t_)*2 + hi) ^ swz)*8]); \
    acc0 = __builtin_amdgcn_mfma_f32_32x32x16_bf16(vf0, pf.v, acc0, 0, 0, 0);     \
    bf16x8 vf1 = *(const bf16x8*)(&Vs[hf][32 + lq][(((su_)*4 + (t_)*2 + hi) ^ swz)*8]);\
    acc1 = __builtin_amdgcn_mfma_f32_32x32x16_bf16(vf1, pf.v, acc1, 0, 0, 0);     \
} while(0)

            __builtin_amdgcn_s_setprio(1);
            PV_SUB(z0, 0, 0, 0);
            PV_SUB(z0, 8, 0, 1);
            if (have1){
                PV_SUB(z1, 0, 1, 0);
                PV_SUB(z1, 8, 1, 1);
            }
            __builtin_amdgcn_s_setprio(0);
#undef PV_SUB
        }
        if (it + 1 < nit) __syncthreads();
    }
    float lt = l + __shfl_xor(l, 32);           // combine the two key-halves (once)
    float rl = 1.0f / lt;
#pragma unroll
    for (int rg = 0; rg < 4; rg++){
        ushort4 o0 = { f2bf(acc0[rg*4+0]*rl), f2bf(acc0[rg*4+1]*rl),
                       f2bf(acc0[rg*4+2]*rl), f2bf(acc0[rg*4+3]*rl) };
        *(ushort4*)(&ob[((size_t)(bb*S_ + qrow))*C_ + h*D_ + rg*8 + hi*4]) = o0;
        ushort4 o1 = { f2bf(acc1[rg*4+0]*rl), f2bf(acc1[rg*4+1]*rl),
                       f2bf(acc1[rg*4+2]*rl), f2bf(acc1[rg*4+3]*rl) };
        *(ushort4*)(&ob[((size_t)(bb*S_ + qrow))*C_ + h*D_ + 32 + rg*8 + hi*4]) = o1;
    }
}

extern "C" void kernel_launch(void* const* d_in, const int* in_sizes, int n_in,
                              void* d_out, int out_size, void* d_ws, size_t ws_size,
                              hipStream_t stream) {
    const float* x     = (const float*)d_in[0];
    const float* Wqkv  = (const float*)d_in[1];
    const float* bqkv  = (const float*)d_in[2];
    const float* Wproj = (const float*)d_in[3];
    const float* bproj = (const float*)d_in[4];
    float* out = (float*)d_out;

    char* ws = (char*)d_ws;
    ushort*   xb   = (ushort*)(ws);                                // 16 MB
    ushort*   wqt  = (ushort*)(ws + (16u<<20));                    // 6 MB
    ushort*   wpt  = (ushort*)(ws + (22u<<20));                    // 2 MB
    unsigned* csT  = (unsigned*)(ws + (24u<<20));                  // 512 KB packed cos|sin [pos][d]
    ushort*   qbuf = (ushort*)(ws + (25u<<20));                    // 16 MB (q pre-scaled, exp2 domain)
    ushort*   kbuf = (ushort*)(ws + (41u<<20));                    // 16 MB
    ushort*   vbuf = (ushort*)(ws + (57u<<20));                    // 16 MB (transposed [bh][D][S])
    ushort*   obuf = (ushort*)(ws + (73u<<20));                    // 16 MB

    k_prep<<<6656, 256, 0, stream>>>(x, Wqkv, Wproj, xb, wqt, wpt, csT);
    k_qkv<<<1536, 256, 0, stream>>>(xb, wqt, bqkv, csT, qbuf, kbuf, vbuf);
    k_attn<<<512, 512, 0, stream>>>(qbuf, kbuf, vbuf, obuf);
    k_proj<<<512, 256, 0, stream>>>(obuf, wpt, bproj, out);
}

// Round 19
// 210.352 us; speedup vs baseline: 1.1292x; 1.1292x over previous
//
#include <hip/hip_runtime.h>
#include <hip/hip_bf16.h>
#include <math.h>

#define B_ 4
#define S_ 2048
#define C_ 1024
#define H_ 16
#define D_ 64
#define M_ (B_*S_)      // 8192
#define NQKV (3*C_)     // 3072
#define KDIM C_         // 1024

typedef float f32x4 __attribute__((ext_vector_type(4)));
typedef float f32x16 __attribute__((ext_vector_type(16)));
typedef short bf16x8 __attribute__((ext_vector_type(8)));

static __device__ __forceinline__ ushort f2bf(float f){
    __hip_bfloat16 h = __float2bfloat16(f);
    union { __hip_bfloat16 b; ushort u; } v; v.b = h;
    return v.u;
}

// async global->LDS, 16B per lane; lds dest = wave-uniform base + lane*16 (linear)
static __device__ __forceinline__ void gload16(const ushort* g, ushort* l){
    __builtin_amdgcn_global_load_lds((__attribute__((address_space(1))) void*)g,
                                     (__attribute__((address_space(3))) void*)l,
                                     16, 0, 0);
}

// ---------------- fused prep: conv x->bf16 | transpose Wqkv | transpose Wproj | cs table ----
__global__ void k_prep(const float* __restrict__ x, const float* __restrict__ Wqkv,
                       const float* __restrict__ Wproj,
                       ushort* __restrict__ xb, ushort* __restrict__ wqt,
                       ushort* __restrict__ wpt, unsigned* __restrict__ csT){
    __shared__ float tile[32][33];
    int blk = blockIdx.x, tid = threadIdx.x;
    if (blk < 2048){
        const int n4 = M_*KDIM/4;
        for (int i = blk*256 + tid; i < n4; i += 2048*256){
            float4 v = *(const float4*)(x + (size_t)i*4);
            ushort4 o = { f2bf(v.x), f2bf(v.y), f2bf(v.z), f2bf(v.w) };
            *(ushort4*)(xb + (size_t)i*4) = o;
        }
    } else if (blk < 5120){
        int t = blk - 2048;                      // 96 x 32 tiles
        int c0 = (t % 96)*32, r0 = (t / 96)*32;
        int tx = tid & 31, ty = tid >> 5;
        for (int j = ty; j < 32; j += 8)
            tile[j][tx] = Wqkv[(size_t)(r0 + j)*NQKV + c0 + tx];
        __syncthreads();
        for (int j = ty; j < 32; j += 8)
            wqt[(size_t)(c0 + tx)*KDIM + r0 + j] = f2bf(tile[j][tx]);
    } else if (blk < 6144){
        int t = blk - 5120;                      // 32 x 32 tiles
        int c0 = (t & 31)*32, r0 = (t >> 5)*32;
        int tx = tid & 31, ty = tid >> 5;
        for (int j = ty; j < 32; j += 8)
            tile[j][tx] = Wproj[(size_t)(r0 + j)*C_ + c0 + tx];
        __syncthreads();
        for (int j = ty; j < 32; j += 8)
            wpt[(size_t)(c0 + tx)*KDIM + r0 + j] = f2bf(tile[j][tx]);
    } else {
        int t = (blk - 6144)*256 + tid;          // S_*D_ = 131072 = 512*256
        int pos = t >> 6, d = t & 63;
        float invf = powf(10000.0f, -(float)(d & 31) / 32.0f);
        float ang = (float)pos * invf;
        csT[t] = (unsigned)f2bf(cosf(ang)) | ((unsigned)f2bf(sinf(ang)) << 16);
    }
}

// ---------------- QKV GEMM (256x128 dbuf) + bias + RoPE + scatter; V transposed ----------------
// q output pre-scaled by 0.125*log2(e) so k_attn's softmax runs in exp2 domain.
__launch_bounds__(512, 4)
__global__ void k_qkv(const ushort* __restrict__ xb, const ushort* __restrict__ wt,
                      const float* __restrict__ bqkv, const unsigned* __restrict__ csT,
                      ushort* __restrict__ qb, ushort* __restrict__ kb, ushort* __restrict__ vT){
    __shared__ __align__(16) ushort As[2][256][32];
    __shared__ __align__(16) ushort Bs[2][128][32];
    int bid = blockIdx.x;                       // 768 blocks, XCD-grouped (A-panel-major)
    int lin = (bid & 7)*96 + (bid >> 3);
    int bx = lin % 24, by = lin / 24;
    int M0 = by*256, N0 = bx*128;
    int tid = threadIdx.x;
    int wid = tid >> 6, lane = tid & 63;
    int wm = wid >> 1, wn = wid & 1;
    int lrow = lane & 15, lk = lane >> 4;
    int swu = (lrow >> 1) & 3;                  // read-side XOR (row bits [2:1])

    int scol = (((lane & 3) ^ ((lane >> 3) & 3))) * 8;   // pre-swizzled source column
    const ushort* gA0 = &xb[(size_t)(M0 + wid*16 + (lane >> 2))*KDIM + scol];
    const ushort* gA1 = gA0 + (size_t)128*KDIM;
    const ushort* gB0 = &wt[(size_t)(N0 + wid*16 + (lane >> 2))*KDIM + scol];

    f32x4 acc[4][4] = {};
    int cur = 0;
    gload16(gA0, &As[0][wid*16][0]);
    gload16(gA1, &As[0][128 + wid*16][0]);
    gload16(gB0, &Bs[0][wid*16][0]);
    __syncthreads();

    for (int k0 = 0; k0 < KDIM; k0 += 32){
        int nk = k0 + 32;
        if (nk < KDIM){                          // prefetch next step into other buffer
            gload16(gA0 + nk, &As[cur^1][wid*16][0]);
            gload16(gA1 + nk, &As[cur^1][128 + wid*16][0]);
            gload16(gB0 + nk, &Bs[cur^1][wid*16][0]);
        }
        bf16x8 a[4], b[4];
#pragma unroll
        for (int mi = 0; mi < 4; mi++)
            a[mi] = *(const bf16x8*)(&As[cur][wm*64 + mi*16 + lrow][(lk ^ swu)*8]);
#pragma unroll
        for (int ni = 0; ni < 4; ni++)
            b[ni] = *(const bf16x8*)(&Bs[cur][wn*64 + ni*16 + lrow][(lk ^ swu)*8]);
#pragma unroll
        for (int mi = 0; mi < 4; mi++)
#pragma unroll
            for (int ni = 0; ni < 4; ni++)
                acc[mi][ni] = __builtin_amdgcn_mfma_f32_16x16x32_bf16(a[mi], b[ni], acc[mi][ni], 0, 0, 0);
        __syncthreads();                          // drains prefetch vmcnt + syncs readers
        cur ^= 1;
    }
#pragma unroll
    for (int mi = 0; mi < 4; mi++)
#pragma unroll
    for (int ni = 0; ni < 4; ni++){
        int gn = N0 + wn*64 + ni*16 + lrow;
        float bias = bqkv[gn];
        int which = gn >> 10;       // 0=q 1=k 2=v (uniform per block: 1024 % 128 == 0)
        int cn = gn & 1023;
        int h = cn >> 6, d = cn & 63;
        int gm0 = M0 + wm*64 + mi*16 + lk*4;
        int bb = gm0 >> 11, pos0 = gm0 & 2047;
        if (which == 2){
            ushort4 o = { f2bf(acc[mi][ni][0] + bias), f2bf(acc[mi][ni][1] + bias),
                          f2bf(acc[mi][ni][2] + bias), f2bf(acc[mi][ni][3] + bias) };
            *(ushort4*)(&vT[(((size_t)(bb*H_ + h))*D_ + d)*S_ + pos0]) = o;
        } else {
#pragma unroll
            for (int rr = 0; rr < 4; rr++){
                float val = acc[mi][ni][rr] + bias;
                float rot = __shfl_xor(val, 1);       // partner col (d^1), bias included
                unsigned cs = csT[(pos0 + rr)*64 + d]; // [pos][d]: d-contiguous, coalesced
                float c = __uint_as_float(cs << 16);
                float s = __uint_as_float(cs & 0xffff0000u);
                float o = val*c + ((d & 1) ? rot : -rot)*s;
                if (which == 0) o *= 0.18033688f;     // (1/sqrt(D)) * log2(e)
                int out_idx = (((bb*H_ + h)*S_) + pos0 + rr)*D_ + d;
                ((which == 0) ? qb : kb)[out_idx] = f2bf(o);
            }
        }
    }
}

// ---------------- proj GEMM (256x128 dbuf) + bias -> fp32 out ----------------
__launch_bounds__(512, 4)
__global__ void k_proj(const ushort* __restrict__ ab, const ushort* __restrict__ wt,
                       const float* __restrict__ bias, float* __restrict__ out){
    __shared__ __align__(16) ushort As[2][256][32];
    __shared__ __align__(16) ushort Bs[2][128][32];
    int bid = blockIdx.x;                       // 256 blocks, XCD-grouped
    int lin = (bid & 7)*32 + (bid >> 3);
    int bx = lin & 7, by = lin >> 3;
    int M0 = by*256, N0 = bx*128;
    int tid = threadIdx.x;
    int wid = tid >> 6, lane = tid & 63;
    int wm = wid >> 1, wn = wid & 1;
    int lrow = lane & 15, lk = lane >> 4;
    int swu = (lrow >> 1) & 3;

    int scol = (((lane & 3) ^ ((lane >> 3) & 3))) * 8;
    const ushort* gA0 = &ab[(size_t)(M0 + wid*16 + (lane >> 2))*KDIM + scol];
    const ushort* gA1 = gA0 + (size_t)128*KDIM;
    const ushort* gB0 = &wt[(size_t)(N0 + wid*16 + (lane >> 2))*KDIM + scol];

    f32x4 acc[4][4] = {};
    int cur = 0;
    gload16(gA0, &As[0][wid*16][0]);
    gload16(gA1, &As[0][128 + wid*16][0]);
    gload16(gB0, &Bs[0][wid*16][0]);
    __syncthreads();

    for (int k0 = 0; k0 < KDIM; k0 += 32){
        int nk = k0 + 32;
        if (nk < KDIM){
            gload16(gA0 + nk, &As[cur^1][wid*16][0]);
            gload16(gA1 + nk, &As[cur^1][128 + wid*16][0]);
            gload16(gB0 + nk, &Bs[cur^1][wid*16][0]);
        }
        bf16x8 a[4], b[4];
#pragma unroll
        for (int mi = 0; mi < 4; mi++)
            a[mi] = *(const bf16x8*)(&As[cur][wm*64 + mi*16 + lrow][(lk ^ swu)*8]);
#pragma unroll
        for (int ni = 0; ni < 4; ni++)
            b[ni] = *(const bf16x8*)(&Bs[cur][wn*64 + ni*16 + lrow][(lk ^ swu)*8]);
#pragma unroll
        for (int mi = 0; mi < 4; mi++)
#pragma unroll
            for (int ni = 0; ni < 4; ni++)
                acc[mi][ni] = __builtin_amdgcn_mfma_f32_16x16x32_bf16(a[mi], b[ni], acc[mi][ni], 0, 0, 0);
        __syncthreads();
        cur ^= 1;
    }
#pragma unroll
    for (int mi = 0; mi < 4; mi++)
#pragma unroll
    for (int ni = 0; ni < 4; ni++){
        int gn = N0 + wn*64 + ni*16 + lrow;
        float bv = bias[gn];
#pragma unroll
        for (int rr = 0; rr < 4; rr++){
            int gm = M0 + wm*64 + mi*16 + lk*4 + rr;
            out[(size_t)gm*C_ + gn] = acc[mi][ni][rr] + bv;
        }
    }
}

// ---------------- causal flash attention: 8 waves x 32 q-rows, NO-MAX softmax, KVBLK=256 ----
// One barrier pair per 256 keys (4 staged 64-key halves, 64 KB LDS, 2 blocks/CU).
// Complementary qt mapping: CU pair (c, c+256) sums to constant 9 tile-iterations.
__launch_bounds__(512, 2)
__global__ void k_attn(const ushort* __restrict__ qb, const ushort* __restrict__ kb,
                       const ushort* __restrict__ vT, ushort* __restrict__ ob){
    __shared__ __align__(16) ushort Ks[4][64][64];
    __shared__ __align__(16) ushort Vs[4][64][64];
    int id = blockIdx.x;
    int bh = id & 63;
    int g  = id >> 6;                           // 0..7
    int qt = (g < 4) ? (7 - g) : (g - 4);       // pairs (7,0),(6,1),(5,2),(4,3)
    int bb = bh >> 4, h = bh & 15;
    int tid = threadIdx.x, wid = tid >> 6, lane = tid & 63;
    int lq = lane & 31, hi = lane >> 5;
    const ushort* qp = qb + (size_t)bh*S_*D_;
    const ushort* kp = kb + (size_t)bh*S_*D_;
    const ushort* vp = vT + (size_t)bh*D_*S_;
    int qw = qt*256 + wid*32;
    int qrow = qw + lq;
    int swz = lq & 7;

    bf16x8 fq[4];                               // Q B-frags: k = c*16 + hi*8 + e
#pragma unroll
    for (int c = 0; c < 4; c++)
        fq[c] = *(const bf16x8*)(&qp[qrow*D_ + c*16 + hi*8]);

    f32x16 acc0 = {}, acc1 = {};                // O^T[d][q]: d = (reg&3)+8*(reg>>2)+4*hi (+32)
    float l = 0.0f;                             // per-lane partial (its key half)

    int sr = tid >> 3, su = tid & 7;            // 512 threads: 64 rows x 8 units per half
    int swr = (su ^ (sr & 7)) * 8;              // swizzled 16B-unit for stage writes
    int sc = su * 8;

    // prologue: tile 0 (256 keys = 4 halves) into regs
    int4 ra[4], rc[4];
#pragma unroll
    for (int q4 = 0; q4 < 4; q4++){
        ra[q4] = *(const int4*)(&kp[(q4*64 + sr)*D_ + sc]);
        rc[q4] = *(const int4*)(&vp[(size_t)sr*S_ + q4*64 + sc]);
    }

    int nit = qt + 1;                           // 256-key tiles
    for (int it = 0; it < nit; ++it){
#pragma unroll
        for (int q4 = 0; q4 < 4; q4++){
            *(int4*)(&Ks[q4][sr][swr]) = ra[q4];
            *(int4*)(&Vs[q4][sr][swr]) = rc[q4];
        }
        __syncthreads();
        if (it + 1 < nit){
            int jn = (it + 1)*256;              // prefetch next 256-key tile; lands during compute
#pragma unroll
            for (int q4 = 0; q4 < 4; q4++){
                ra[q4] = *(const int4*)(&kp[(jn + q4*64 + sr)*D_ + sc]);
                rc[q4] = *(const int4*)(&vp[(size_t)sr*S_ + jn + q4*64 + sc]);
            }
        }
#pragma unroll
        for (int hf = 0; hf < 4; hf++){
            int relh = qw - it*256 - hf*64;     // wave-uniform; 32-aligned
            if (relh < 0) continue;
            bool diag0 = (relh == 0);
            bool have1 = (relh >= 32);
            bool diag1 = (relh == 32);
            f32x16 z0 = {}, z1 = {};
            __builtin_amdgcn_s_setprio(1);
#pragma unroll
            for (int c = 0; c < 4; c++){
                bf16x8 kf = *(const bf16x8*)(&Ks[hf][lq][((2*c + hi) ^ swz)*8]);
                z0 = __builtin_amdgcn_mfma_f32_32x32x16_bf16(kf, fq[c], z0, 0, 0, 0);
            }
            if (have1){
#pragma unroll
                for (int c = 0; c < 4; c++){
                    bf16x8 kf = *(const bf16x8*)(&Ks[hf][32 + lq][((2*c + hi) ^ swz)*8]);
                    z1 = __builtin_amdgcn_mfma_f32_32x32x16_bf16(kf, fq[c], z1, 0, 0, 0);
                }
            }
            __builtin_amdgcn_s_setprio(0);
            if (diag0){
#pragma unroll
                for (int r = 0; r < 16; r++)
                    if (((r & 3) + 8*(r >> 2) + 4*hi) > lq) z0[r] = -1e30f;
            }
            if (diag1){
#pragma unroll
                for (int r = 0; r < 16; r++)
                    if (((r & 3) + 8*(r >> 2) + 4*hi) > lq) z1[r] = -1e30f;
            }
            // no-max softmax: p = exp2(z) direct; masked -> exp2(-1e30) = 0
#pragma unroll
            for (int r = 0; r < 16; r++){ z0[r] = exp2f(z0[r]); l += z0[r]; }
            if (have1){
#pragma unroll
                for (int r = 0; r < 16; r++){ z1[r] = exp2f(z1[r]); l += z1[r]; }
            }

            // P->bf16 B-frags in-register: per 16-key sub, 4 cvt_pk + 2 permlane32_swap.
#define PV_SUB(zz, r0_, su_, t_) do {                                             \
    unsigned w0, w1, w2, w3;                                                      \
    asm("v_cvt_pk_bf16_f32 %0, %1, %2" : "=v"(w0) : "v"(zz[r0_+0]), "v"(zz[r0_+1])); \
    asm("v_cvt_pk_bf16_f32 %0, %1, %2" : "=v"(w1) : "v"(zz[r0_+2]), "v"(zz[r0_+3])); \
    asm("v_cvt_pk_bf16_f32 %0, %1, %2" : "=v"(w2) : "v"(zz[r0_+4]), "v"(zz[r0_+5])); \
    asm("v_cvt_pk_bf16_f32 %0, %1, %2" : "=v"(w3) : "v"(zz[r0_+6]), "v"(zz[r0_+7])); \
    auto s02 = __builtin_amdgcn_permlane32_swap(w0, w2, false, false);             \
    auto s13 = __builtin_amdgcn_permlane32_swap(w1, w3, false, false);             \
    union { unsigned u[4]; bf16x8 v; } pf;                                        \
    pf.u[0] = s02[0]; pf.u[1] = s13[0]; pf.u[2] = s02[1]; pf.u[3] = s13[1];       \
    bf16x8 vf0 = *(const bf16x8*)(&Vs[hf][lq][(((su_)*4 + (t_)*2 + hi) ^ swz)*8]); \
    acc0 = __builtin_amdgcn_mfma_f32_32x32x16_bf16(vf0, pf.v, acc0, 0, 0, 0);     \
    bf16x8 vf1 = *(const bf16x8*)(&Vs[hf][32 + lq][(((su_)*4 + (t_)*2 + hi) ^ swz)*8]);\
    acc1 = __builtin_amdgcn_mfma_f32_32x32x16_bf16(vf1, pf.v, acc1, 0, 0, 0);     \
} while(0)

            __builtin_amdgcn_s_setprio(1);
            PV_SUB(z0, 0, 0, 0);
            PV_SUB(z0, 8, 0, 1);
            if (have1){
                PV_SUB(z1, 0, 1, 0);
                PV_SUB(z1, 8, 1, 1);
            }
            __builtin_amdgcn_s_setprio(0);
#undef PV_SUB
        }
        if (it + 1 < nit) __syncthreads();
    }
    float lt = l + __shfl_xor(l, 32);           // combine the two key-halves (once)
    float rl = 1.0f / lt;
#pragma unroll
    for (int rg = 0; rg < 4; rg++){
        ushort4 o0 = { f2bf(acc0[rg*4+0]*rl), f2bf(acc0[rg*4+1]*rl),
                       f2bf(acc0[rg*4+2]*rl), f2bf(acc0[rg*4+3]*rl) };
        *(ushort4*)(&ob[((size_t)(bb*S_ + qrow))*C_ + h*D_ + rg*8 + hi*4]) = o0;
        ushort4 o1 = { f2bf(acc1[rg*4+0]*rl), f2bf(acc1[rg*4+1]*rl),
                       f2bf(acc1[rg*4+2]*rl), f2bf(acc1[rg*4+3]*rl) };
        *(ushort4*)(&ob[((size_t)(bb*S_ + qrow))*C_ + h*D_ + 32 + rg*8 + hi*4]) = o1;
    }
}

extern "C" void kernel_launch(void* const* d_in, const int* in_sizes, int n_in,
                              void* d_out, int out_size, void* d_ws, size_t ws_size,
                              hipStream_t stream) {
    const float* x     = (const float*)d_in[0];
    const float* Wqkv  = (const float*)d_in[1];
    const float* bqkv  = (const float*)d_in[2];
    const float* Wproj = (const float*)d_in[3];
    const float* bproj = (const float*)d_in[4];
    float* out = (float*)d_out;

    char* ws = (char*)d_ws;
    ushort*   xb   = (ushort*)(ws);                                // 16 MB
    ushort*   wqt  = (ushort*)(ws + (16u<<20));                    // 6 MB
    ushort*   wpt  = (ushort*)(ws + (22u<<20));                    // 2 MB
    unsigned* csT  = (unsigned*)(ws + (24u<<20));                  // 512 KB packed cos|sin [pos][d]
    ushort*   qbuf = (ushort*)(ws + (25u<<20));                    // 16 MB (q pre-scaled, exp2 domain)
    ushort*   kbuf = (ushort*)(ws + (41u<<20));                    // 16 MB
    ushort*   vbuf = (ushort*)(ws + (57u<<20));                    // 16 MB (transposed [bh][D][S])
    ushort*   obuf = (ushort*)(ws + (73u<<20));                    // 16 MB

    k_prep<<<6656, 256, 0, stream>>>(x, Wqkv, Wproj, xb, wqt, wpt, csT);
    k_qkv<<<768, 512, 0, stream>>>(xb, wqt, bqkv, csT, qbuf, kbuf, vbuf);
    k_attn<<<512, 512, 0, stream>>>(qbuf, kbuf, vbuf, obuf);
    k_proj<<<256, 512, 0, stream>>>(obuf, wpt, bproj, out);
}

// Round 20
// 175.752 us; speedup vs baseline: 1.3516x; 1.1969x over previous
//
#include <hip/hip_runtime.h>
#include <hip/hip_bf16.h>
#include <math.h>

#define B_ 4
#define S_ 2048
#define C_ 1024
#define H_ 16
#define D_ 64
#define M_ (B_*S_)      // 8192
#define NQKV (3*C_)     // 3072
#define KDIM C_         // 1024

typedef float f32x4 __attribute__((ext_vector_type(4)));
typedef float f32x16 __attribute__((ext_vector_type(16)));
typedef short bf16x8 __attribute__((ext_vector_type(8)));

static __device__ __forceinline__ ushort f2bf(float f){
    __hip_bfloat16 h = __float2bfloat16(f);
    union { __hip_bfloat16 b; ushort u; } v; v.b = h;
    return v.u;
}

// async global->LDS, 16B per lane; lds dest = wave-uniform base + lane*16 (linear)
static __device__ __forceinline__ void gload16(const ushort* g, ushort* l){
    __builtin_amdgcn_global_load_lds((__attribute__((address_space(1))) void*)g,
                                     (__attribute__((address_space(3))) void*)l,
                                     16, 0, 0);
}

// ---------------- fused prep: conv x->bf16 | transpose Wqkv | transpose Wproj | cs table ----
__global__ void k_prep(const float* __restrict__ x, const float* __restrict__ Wqkv,
                       const float* __restrict__ Wproj,
                       ushort* __restrict__ xb, ushort* __restrict__ wqt,
                       ushort* __restrict__ wpt, unsigned* __restrict__ csT){
    __shared__ float tile[32][33];
    int blk = blockIdx.x, tid = threadIdx.x;
    if (blk < 2048){
        const int n4 = M_*KDIM/4;
        for (int i = blk*256 + tid; i < n4; i += 2048*256){
            float4 v = *(const float4*)(x + (size_t)i*4);
            ushort4 o = { f2bf(v.x), f2bf(v.y), f2bf(v.z), f2bf(v.w) };
            *(ushort4*)(xb + (size_t)i*4) = o;
        }
    } else if (blk < 5120){
        int t = blk - 2048;                      // 96 x 32 tiles
        int c0 = (t % 96)*32, r0 = (t / 96)*32;
        int tx = tid & 31, ty = tid >> 5;
        for (int j = ty; j < 32; j += 8)
            tile[j][tx] = Wqkv[(size_t)(r0 + j)*NQKV + c0 + tx];
        __syncthreads();
        for (int j = ty; j < 32; j += 8)
            wqt[(size_t)(c0 + tx)*KDIM + r0 + j] = f2bf(tile[j][tx]);
    } else if (blk < 6144){
        int t = blk - 5120;                      // 32 x 32 tiles
        int c0 = (t & 31)*32, r0 = (t >> 5)*32;
        int tx = tid & 31, ty = tid >> 5;
        for (int j = ty; j < 32; j += 8)
            tile[j][tx] = Wproj[(size_t)(r0 + j)*C_ + c0 + tx];
        __syncthreads();
        for (int j = ty; j < 32; j += 8)
            wpt[(size_t)(c0 + tx)*KDIM + r0 + j] = f2bf(tile[j][tx]);
    } else {
        int t = (blk - 6144)*256 + tid;          // S_*D_ = 131072 = 512*256
        int pos = t >> 6, d = t & 63;
        float invf = powf(10000.0f, -(float)(d & 31) / 32.0f);
        float ang = (float)pos * invf;
        csT[t] = (unsigned)f2bf(cosf(ang)) | ((unsigned)f2bf(sinf(ang)) << 16);
    }
}

// ---------------- QKV GEMM (256x128 dbuf) + bias + RoPE + scatter; V transposed ----------------
// q output pre-scaled by 0.125*log2(e) so k_attn's softmax runs in exp2 domain.
__launch_bounds__(512, 4)
__global__ void k_qkv(const ushort* __restrict__ xb, const ushort* __restrict__ wt,
                      const float* __restrict__ bqkv, const unsigned* __restrict__ csT,
                      ushort* __restrict__ qb, ushort* __restrict__ kb, ushort* __restrict__ vT){
    __shared__ __align__(16) ushort As[2][256][32];
    __shared__ __align__(16) ushort Bs[2][128][32];
    int bid = blockIdx.x;                       // 768 blocks, XCD-grouped (A-panel-major)
    int lin = (bid & 7)*96 + (bid >> 3);
    int bx = lin % 24, by = lin / 24;
    int M0 = by*256, N0 = bx*128;
    int tid = threadIdx.x;
    int wid = tid >> 6, lane = tid & 63;
    int wm = wid >> 1, wn = wid & 1;
    int lrow = lane & 15, lk = lane >> 4;
    int swu = (lrow >> 1) & 3;                  // read-side XOR (row bits [2:1])

    int scol = (((lane & 3) ^ ((lane >> 3) & 3))) * 8;   // pre-swizzled source column
    const ushort* gA0 = &xb[(size_t)(M0 + wid*16 + (lane >> 2))*KDIM + scol];
    const ushort* gA1 = gA0 + (size_t)128*KDIM;
    const ushort* gB0 = &wt[(size_t)(N0 + wid*16 + (lane >> 2))*KDIM + scol];

    f32x4 acc[4][4] = {};
    int cur = 0;
    gload16(gA0, &As[0][wid*16][0]);
    gload16(gA1, &As[0][128 + wid*16][0]);
    gload16(gB0, &Bs[0][wid*16][0]);
    __syncthreads();

    for (int k0 = 0; k0 < KDIM; k0 += 32){
        int nk = k0 + 32;
        if (nk < KDIM){                          // prefetch next step into other buffer
            gload16(gA0 + nk, &As[cur^1][wid*16][0]);
            gload16(gA1 + nk, &As[cur^1][128 + wid*16][0]);
            gload16(gB0 + nk, &Bs[cur^1][wid*16][0]);
        }
        bf16x8 a[4], b[4];
#pragma unroll
        for (int mi = 0; mi < 4; mi++)
            a[mi] = *(const bf16x8*)(&As[cur][wm*64 + mi*16 + lrow][(lk ^ swu)*8]);
#pragma unroll
        for (int ni = 0; ni < 4; ni++)
            b[ni] = *(const bf16x8*)(&Bs[cur][wn*64 + ni*16 + lrow][(lk ^ swu)*8]);
#pragma unroll
        for (int mi = 0; mi < 4; mi++)
#pragma unroll
            for (int ni = 0; ni < 4; ni++)
                acc[mi][ni] = __builtin_amdgcn_mfma_f32_16x16x32_bf16(a[mi], b[ni], acc[mi][ni], 0, 0, 0);
        __syncthreads();                          // drains prefetch vmcnt + syncs readers
        cur ^= 1;
    }
#pragma unroll
    for (int mi = 0; mi < 4; mi++)
#pragma unroll
    for (int ni = 0; ni < 4; ni++){
        int gn = N0 + wn*64 + ni*16 + lrow;
        float bias = bqkv[gn];
        int which = gn >> 10;       // 0=q 1=k 2=v (uniform per block: 1024 % 128 == 0)
        int cn = gn & 1023;
        int h = cn >> 6, d = cn & 63;
        int gm0 = M0 + wm*64 + mi*16 + lk*4;
        int bb = gm0 >> 11, pos0 = gm0 & 2047;
        if (which == 2){
            ushort4 o = { f2bf(acc[mi][ni][0] + bias), f2bf(acc[mi][ni][1] + bias),
                          f2bf(acc[mi][ni][2] + bias), f2bf(acc[mi][ni][3] + bias) };
            *(ushort4*)(&vT[(((size_t)(bb*H_ + h))*D_ + d)*S_ + pos0]) = o;
        } else {
#pragma unroll
            for (int rr = 0; rr < 4; rr++){
                float val = acc[mi][ni][rr] + bias;
                float rot = __shfl_xor(val, 1);       // partner col (d^1), bias included
                unsigned cs = csT[(pos0 + rr)*64 + d]; // [pos][d]: d-contiguous, coalesced
                float c = __uint_as_float(cs << 16);
                float s = __uint_as_float(cs & 0xffff0000u);
                float o = val*c + ((d & 1) ? rot : -rot)*s;
                if (which == 0) o *= 0.18033688f;     // (1/sqrt(D)) * log2(e)
                int out_idx = (((bb*H_ + h)*S_) + pos0 + rr)*D_ + d;
                ((which == 0) ? qb : kb)[out_idx] = f2bf(o);
            }
        }
    }
}

// ---------------- proj GEMM (256x128 dbuf) + bias -> fp32 out ----------------
__launch_bounds__(512, 4)
__global__ void k_proj(const ushort* __restrict__ ab, const ushort* __restrict__ wt,
                       const float* __restrict__ bias, float* __restrict__ out){
    __shared__ __align__(16) ushort As[2][256][32];
    __shared__ __align__(16) ushort Bs[2][128][32];
    int bid = blockIdx.x;                       // 256 blocks, XCD-grouped
    int lin = (bid & 7)*32 + (bid >> 3);
    int bx = lin & 7, by = lin >> 3;
    int M0 = by*256, N0 = bx*128;
    int tid = threadIdx.x;
    int wid = tid >> 6, lane = tid & 63;
    int wm = wid >> 1, wn = wid & 1;
    int lrow = lane & 15, lk = lane >> 4;
    int swu = (lrow >> 1) & 3;

    int scol = (((lane & 3) ^ ((lane >> 3) & 3))) * 8;
    const ushort* gA0 = &ab[(size_t)(M0 + wid*16 + (lane >> 2))*KDIM + scol];
    const ushort* gA1 = gA0 + (size_t)128*KDIM;
    const ushort* gB0 = &wt[(size_t)(N0 + wid*16 + (lane >> 2))*KDIM + scol];

    f32x4 acc[4][4] = {};
    int cur = 0;
    gload16(gA0, &As[0][wid*16][0]);
    gload16(gA1, &As[0][128 + wid*16][0]);
    gload16(gB0, &Bs[0][wid*16][0]);
    __syncthreads();

    for (int k0 = 0; k0 < KDIM; k0 += 32){
        int nk = k0 + 32;
        if (nk < KDIM){
            gload16(gA0 + nk, &As[cur^1][wid*16][0]);
            gload16(gA1 + nk, &As[cur^1][128 + wid*16][0]);
            gload16(gB0 + nk, &Bs[cur^1][wid*16][0]);
        }
        bf16x8 a[4], b[4];
#pragma unroll
        for (int mi = 0; mi < 4; mi++)
            a[mi] = *(const bf16x8*)(&As[cur][wm*64 + mi*16 + lrow][(lk ^ swu)*8]);
#pragma unroll
        for (int ni = 0; ni < 4; ni++)
            b[ni] = *(const bf16x8*)(&Bs[cur][wn*64 + ni*16 + lrow][(lk ^ swu)*8]);
#pragma unroll
        for (int mi = 0; mi < 4; mi++)
#pragma unroll
            for (int ni = 0; ni < 4; ni++)
                acc[mi][ni] = __builtin_amdgcn_mfma_f32_16x16x32_bf16(a[mi], b[ni], acc[mi][ni], 0, 0, 0);
        __syncthreads();
        cur ^= 1;
    }
#pragma unroll
    for (int mi = 0; mi < 4; mi++)
#pragma unroll
    for (int ni = 0; ni < 4; ni++){
        int gn = N0 + wn*64 + ni*16 + lrow;
        float bv = bias[gn];
#pragma unroll
        for (int rr = 0; rr < 4; rr++){
            int gm = M0 + wm*64 + mi*16 + lk*4 + rr;
            out[(size_t)gm*C_ + gn] = acc[mi][ni][rr] + bv;
        }
    }
}

// ---------------- causal flash attention: 8 waves x 32 q-rows, NO-MAX softmax, KVBLK=128 ----
// One barrier pair per 128 keys.  Complementary qt mapping: CU pair sums to constant work.
__launch_bounds__(512, 2)
__global__ void k_attn(const ushort* __restrict__ qb, const ushort* __restrict__ kb,
                       const ushort* __restrict__ vT, ushort* __restrict__ ob){
    __shared__ __align__(16) ushort Ks[2][64][64];
    __shared__ __align__(16) ushort Vs[2][64][64];
    int id = blockIdx.x;
    int bh = id & 63;
    int g  = id >> 6;                           // 0..7
    int qt = (g < 4) ? (7 - g) : (g - 4);       // pairs (7,0),(6,1),(5,2),(4,3)
    int bb = bh >> 4, h = bh & 15;
    int tid = threadIdx.x, wid = tid >> 6, lane = tid & 63;
    int lq = lane & 31, hi = lane >> 5;
    const ushort* qp = qb + (size_t)bh*S_*D_;
    const ushort* kp = kb + (size_t)bh*S_*D_;
    const ushort* vp = vT + (size_t)bh*D_*S_;
    int qw = qt*256 + wid*32;
    int qrow = qw + lq;
    int swz = lq & 7;

    bf16x8 fq[4];                               // Q B-frags: k = c*16 + hi*8 + e
#pragma unroll
    for (int c = 0; c < 4; c++)
        fq[c] = *(const bf16x8*)(&qp[qrow*D_ + c*16 + hi*8]);

    f32x16 acc0 = {}, acc1 = {};                // O^T[d][q]: d = (reg&3)+8*(reg>>2)+4*hi (+32)
    float l = 0.0f;                             // per-lane partial (its key half)

    int sr = tid >> 3, su = tid & 7;            // 512 threads: 64 rows x 8 units per half
    int swr = (su ^ (sr & 7)) * 8;              // swizzled 16B-unit for stage writes
    int sc = su * 8;

    // prologue: tile 0 (128 keys = 2 halves) into regs
    int4 ra0 = *(const int4*)(&kp[sr*D_ + sc]);
    int4 ra1 = *(const int4*)(&kp[(64 + sr)*D_ + sc]);
    int4 rc0 = *(const int4*)(&vp[(size_t)sr*S_ + sc]);
    int4 rc1 = *(const int4*)(&vp[(size_t)sr*S_ + 64 + sc]);

    int nit = 2*qt + 2;                         // 128-key tiles
    for (int it = 0; it < nit; ++it){
        *(int4*)(&Ks[0][sr][swr]) = ra0;
        *(int4*)(&Ks[1][sr][swr]) = ra1;
        *(int4*)(&Vs[0][sr][swr]) = rc0;
        *(int4*)(&Vs[1][sr][swr]) = rc1;
        __syncthreads();
        if (it + 1 < nit){
            int jn = (it + 1)*128;              // prefetch next 128-key tile; lands during compute
            ra0 = *(const int4*)(&kp[(jn + sr)*D_ + sc]);
            ra1 = *(const int4*)(&kp[(jn + 64 + sr)*D_ + sc]);
            rc0 = *(const int4*)(&vp[(size_t)sr*S_ + jn + sc]);
            rc1 = *(const int4*)(&vp[(size_t)sr*S_ + jn + 64 + sc]);
        }
#pragma unroll
        for (int hf = 0; hf < 2; hf++){
            int relh = qw - it*128 - hf*64;     // wave-uniform; 32-aligned
            if (relh < 0) continue;
            bool diag0 = (relh == 0);
            bool have1 = (relh >= 32);
            bool diag1 = (relh == 32);
            f32x16 z0 = {}, z1 = {};
            __builtin_amdgcn_s_setprio(1);
#pragma unroll
            for (int c = 0; c < 4; c++){
                bf16x8 kf = *(const bf16x8*)(&Ks[hf][lq][((2*c + hi) ^ swz)*8]);
                z0 = __builtin_amdgcn_mfma_f32_32x32x16_bf16(kf, fq[c], z0, 0, 0, 0);
            }
            if (have1){
#pragma unroll
                for (int c = 0; c < 4; c++){
                    bf16x8 kf = *(const bf16x8*)(&Ks[hf][32 + lq][((2*c + hi) ^ swz)*8]);
                    z1 = __builtin_amdgcn_mfma_f32_32x32x16_bf16(kf, fq[c], z1, 0, 0, 0);
                }
            }
            __builtin_amdgcn_s_setprio(0);
            if (diag0){
#pragma unroll
                for (int r = 0; r < 16; r++)
                    if (((r & 3) + 8*(r >> 2) + 4*hi) > lq) z0[r] = -1e30f;
            }
            if (diag1){
#pragma unroll
                for (int r = 0; r < 16; r++)
                    if (((r & 3) + 8*(r >> 2) + 4*hi) > lq) z1[r] = -1e30f;
            }
            // no-max softmax: p = exp2(z) direct; masked -> exp2(-1e30) = 0
#pragma unroll
            for (int r = 0; r < 16; r++){ z0[r] = exp2f(z0[r]); l += z0[r]; }
            if (have1){
#pragma unroll
                for (int r = 0; r < 16; r++){ z1[r] = exp2f(z1[r]); l += z1[r]; }
            }

            // P->bf16 B-frags in-register: per 16-key sub, 4 cvt_pk + 2 permlane32_swap.
#define PV_SUB(zz, r0_, su_, t_) do {                                             \
    unsigned w0, w1, w2, w3;                                                      \
    asm("v_cvt_pk_bf16_f32 %0, %1, %2" : "=v"(w0) : "v"(zz[r0_+0]), "v"(zz[r0_+1])); \
    asm("v_cvt_pk_bf16_f32 %0, %1, %2" : "=v"(w1) : "v"(zz[r0_+2]), "v"(zz[r0_+3])); \
    asm("v_cvt_pk_bf16_f32 %0, %1, %2" : "=v"(w2) : "v"(zz[r0_+4]), "v"(zz[r0_+5])); \
    asm("v_cvt_pk_bf16_f32 %0, %1, %2" : "=v"(w3) : "v"(zz[r0_+6]), "v"(zz[r0_+7])); \
    auto s02 = __builtin_amdgcn_permlane32_swap(w0, w2, false, false);             \
    auto s13 = __builtin_amdgcn_permlane32_swap(w1, w3, false, false);             \
    union { unsigned u[4]; bf16x8 v; } pf;                                        \
    pf.u[0] = s02[0]; pf.u[1] = s13[0]; pf.u[2] = s02[1]; pf.u[3] = s13[1];       \
    bf16x8 vf0 = *(const bf16x8*)(&Vs[hf][lq][(((su_)*4 + (t_)*2 + hi) ^ swz)*8]); \
    acc0 = __builtin_amdgcn_mfma_f32_32x32x16_bf16(vf0, pf.v, acc0, 0, 0, 0);     \
    bf16x8 vf1 = *(const bf16x8*)(&Vs[hf][32 + lq][(((su_)*4 + (t_)*2 + hi) ^ swz)*8]);\
    acc1 = __builtin_amdgcn_mfma_f32_32x32x16_bf16(vf1, pf.v, acc1, 0, 0, 0);     \
} while(0)

            __builtin_amdgcn_s_setprio(1);
            PV_SUB(z0, 0, 0, 0);
            PV_SUB(z0, 8, 0, 1);
            if (have1){
                PV_SUB(z1, 0, 1, 0);
                PV_SUB(z1, 8, 1, 1);
            }
            __builtin_amdgcn_s_setprio(0);
#undef PV_SUB
        }
        if (it + 1 < nit) __syncthreads();
    }
    float lt = l + __shfl_xor(l, 32);           // combine the two key-halves (once)
    float rl = 1.0f / lt;
#pragma unroll
    for (int rg = 0; rg < 4; rg++){
        ushort4 o0 = { f2bf(acc0[rg*4+0]*rl), f2bf(acc0[rg*4+1]*rl),
                       f2bf(acc0[rg*4+2]*rl), f2bf(acc0[rg*4+3]*rl) };
        *(ushort4*)(&ob[((size_t)(bb*S_ + qrow))*C_ + h*D_ + rg*8 + hi*4]) = o0;
        ushort4 o1 = { f2bf(acc1[rg*4+0]*rl), f2bf(acc1[rg*4+1]*rl),
                       f2bf(acc1[rg*4+2]*rl), f2bf(acc1[rg*4+3]*rl) };
        *(ushort4*)(&ob[((size_t)(bb*S_ + qrow))*C_ + h*D_ + 32 + rg*8 + hi*4]) = o1;
    }
}

extern "C" void kernel_launch(void* const* d_in, const int* in_sizes, int n_in,
                              void* d_out, int out_size, void* d_ws, size_t ws_size,
                              hipStream_t stream) {
    const float* x     = (const float*)d_in[0];
    const float* Wqkv  = (const float*)d_in[1];
    const float* bqkv  = (const float*)d_in[2];
    const float* Wproj = (const float*)d_in[3];
    const float* bproj = (const float*)d_in[4];
    float* out = (float*)d_out;

    char* ws = (char*)d_ws;
    ushort*   xb   = (ushort*)(ws);                                // 16 MB
    ushort*   wqt  = (ushort*)(ws + (16u<<20));                    // 6 MB
    ushort*   wpt  = (ushort*)(ws + (22u<<20));                    // 2 MB
    unsigned* csT  = (unsigned*)(ws + (24u<<20));                  // 512 KB packed cos|sin [pos][d]
    ushort*   qbuf = (ushort*)(ws + (25u<<20));                    // 16 MB (q pre-scaled, exp2 domain)
    ushort*   kbuf = (ushort*)(ws + (41u<<20));                    // 16 MB
    ushort*   vbuf = (ushort*)(ws + (57u<<20));                    // 16 MB (transposed [bh][D][S])
    ushort*   obuf = (ushort*)(ws + (73u<<20));                    // 16 MB

    k_prep<<<6656, 256, 0, stream>>>(x, Wqkv, Wproj, xb, wqt, wpt, csT);
    k_qkv<<<768, 512, 0, stream>>>(xb, wqt, bqkv, csT, qbuf, kbuf, vbuf);
    k_attn<<<512, 512, 0, stream>>>(qbuf, kbuf, vbuf, obuf);
    k_proj<<<256, 512, 0, stream>>>(obuf, wpt, bproj, out);
}